// Round 1
// baseline (2479.076 us; speedup 1.0000x reference)
//
#include <hip/hip_runtime.h>
#include <math.h>

#define NN 500000
#define MM 400000
#define DD 32
#define CC 16
#define KNNB 6
#define KK 10
#define HH 64
#define IN_MAIN 51
#define TBLK 256

// ---------------------------------------------------------------------------
// Tiny prep kernel: transpose the 64xKout second-layer weights to Koutx64 so
// the main kernel's per-output dot products read contiguous rows (scalar
// s_load friendly).
// ---------------------------------------------------------------------------
__global__ void transpose_w2_kernel(const float* __restrict__ w2,
                                    float* __restrict__ w2t, int kout) {
    int idx = blockIdx.x * blockDim.x + threadIdx.x;
    if (idx < HH * kout) {
        int h = idx / kout, j = idx % kout;
        w2t[j * HH + h] = w2[idx];
    }
}

// hid[h] += x[i] * w1[i][h]; weights wave-uniform (scalar loads), x from the
// thread's private LDS column (dynamic index without scratch).
template <int NIN>
__device__ __forceinline__ void hidden_layer(const float* __restrict__ w1,
                                             const float* __restrict__ b1,
                                             const float* xl, int tid,
                                             float hid[64]) {
#pragma unroll
    for (int h = 0; h < 64; ++h) hid[h] = b1[h];
    for (int i = 0; i < NIN; ++i) {
        float xv = xl[i * TBLK + tid];
        const float* wr = w1 + i * 64;
#pragma unroll
        for (int h = 0; h < 64; ++h) hid[h] = fmaf(xv, wr[h], hid[h]);
    }
#pragma unroll
    for (int h = 0; h < 64; ++h) hid[h] = fmaxf(hid[h], 0.0f);
}

__device__ __forceinline__ float dot64(const float* __restrict__ wt,
                                       const float hid[64], float acc) {
#pragma unroll
    for (int h = 0; h < 64; ++h) acc = fmaf(hid[h], wt[h], acc);
    return acc;
}

__global__ __launch_bounds__(TBLK, 2) void gif_main_kernel(
    const float* __restrict__ cam, const float* __restrict__ anchors,
    const float* __restrict__ scales, const float* __restrict__ feat,
    const float* __restrict__ timef, const float* __restrict__ factors,
    const float* __restrict__ op_w1, const float* __restrict__ op_b1,
    const float* __restrict__ op_b2, const float* __restrict__ col_w1,
    const float* __restrict__ col_b1, const float* __restrict__ col_b2,
    const float* __restrict__ cov_w1, const float* __restrict__ cov_b1,
    const float* __restrict__ cov_b2, const float* __restrict__ mot_w1,
    const float* __restrict__ mot_b1, const float* __restrict__ mot_b2,
    const float* __restrict__ w2t, const int* __restrict__ visible_idx,
    const int* __restrict__ knn_idx, float* __restrict__ out_mk,
    float* __restrict__ out_m) {
    __shared__ float xlds[64 * TBLK];  // 64 KiB: per-thread input column
    const int tid = threadIdx.x;
    const int p = blockIdx.x * TBLK + tid;
    if (p >= MM) return;  // no barriers below -> early-exit is safe
    float* xl = xlds;

    const int vid = visible_idx[p];

    const float4 fac = *(const float4*)(factors + (size_t)vid * 4);
    const float tff = fac.x, mf = fac.y, kf = fac.z, pf = fac.w;

    // view direction
    const float cx = cam[3], cy = cam[7], cz = cam[11];
    const float ax = anchors[(size_t)vid * 3 + 0];
    const float ay = anchors[(size_t)vid * 3 + 1];
    const float az = anchors[(size_t)vid * 3 + 2];
    const float vx = ax - cx, vy = ay - cy, vz = az - cz;
    const float nrm = sqrtf(vx * vx + vy * vy + vz * vz);
    const float inv = 1.0f / fmaxf(nrm, 1e-8f);

    // ---- stage taf = [sel_feat(0..31), vdn(32..34), tf_scaled(35..50)] ----
    const float4* fp = (const float4*)(feat + (size_t)vid * DD);
#pragma unroll
    for (int q = 0; q < 8; ++q) {
        float4 v = fp[q];
        xl[(q * 4 + 0) * TBLK + tid] = v.x;
        xl[(q * 4 + 1) * TBLK + tid] = v.y;
        xl[(q * 4 + 2) * TBLK + tid] = v.z;
        xl[(q * 4 + 3) * TBLK + tid] = v.w;
    }
    xl[32 * TBLK + tid] = vx * inv;
    xl[33 * TBLK + tid] = vy * inv;
    xl[34 * TBLK + tid] = vz * inv;
    // tf_slice row = one 64B line at float offset vid*256 + 112
    const float4* tp = (const float4*)(timef + (size_t)vid * 256 + 112);
#pragma unroll
    for (int q = 0; q < 4; ++q) {
        float4 v = tp[q];
        xl[(35 + q * 4 + 0) * TBLK + tid] = v.x * tff;
        xl[(35 + q * 4 + 1) * TBLK + tid] = v.y * tff;
        xl[(35 + q * 4 + 2) * TBLK + tid] = v.z * tff;
        xl[(35 + q * 4 + 3) * TBLK + tid] = v.w * tff;
    }

    // ---- KNN means (kept in registers across the 3 main MLPs) ----
    float kn_f[DD], kn_t[CC];
#pragma unroll
    for (int d = 0; d < DD; ++d) kn_f[d] = 0.0f;
#pragma unroll
    for (int c = 0; c < CC; ++c) kn_t[c] = 0.0f;
    for (int nb = 0; nb < KNNB; ++nb) {
        const int nid = knn_idx[(size_t)vid * KNNB + nb];
        const float4* nf = (const float4*)(feat + (size_t)nid * DD);
#pragma unroll
        for (int q = 0; q < 8; ++q) {
            float4 v = nf[q];
            kn_f[q * 4 + 0] += v.x;
            kn_f[q * 4 + 1] += v.y;
            kn_f[q * 4 + 2] += v.z;
            kn_f[q * 4 + 3] += v.w;
        }
        const float4* nt = (const float4*)(timef + (size_t)nid * 256 + 112);
#pragma unroll
        for (int q = 0; q < 4; ++q) {
            float4 v = nt[q];
            kn_t[q * 4 + 0] += v.x;
            kn_t[q * 4 + 1] += v.y;
            kn_t[q * 4 + 2] += v.z;
            kn_t[q * 4 + 3] += v.w;
        }
    }
    const float inv6 = 1.0f / 6.0f;
#pragma unroll
    for (int d = 0; d < DD; ++d) kn_f[d] *= inv6;
#pragma unroll
    for (int c = 0; c < CC; ++c) kn_t[c] *= inv6;

    float hid[64];
    const size_t mkbase = (size_t)p * 10;

    // ---- OP head: tanh(.)*pf -> column 0 ----
    hidden_layer<IN_MAIN>(op_w1, op_b1, xl, tid, hid);
    for (int j = 0; j < KK; ++j) {
        float acc = dot64(w2t + j * 64, hid, op_b2[j]);
        out_mk[(mkbase + j) * 11 + 0] = tanhf(acc) * pf;
    }
    // ---- COL head: sigmoid -> columns 1..3 ----
    hidden_layer<IN_MAIN>(col_w1, col_b1, xl, tid, hid);
    for (int j = 0; j < 30; ++j) {
        float acc = dot64(w2t + 640 + j * 64, hid, col_b2[j]);
        float s = 1.0f / (1.0f + expf(-acc));
        out_mk[(mkbase + j / 3) * 11 + 1 + j % 3] = s;
    }
    // ---- COV head: linear -> columns 4..10 ----
    hidden_layer<IN_MAIN>(cov_w1, cov_b1, xl, tid, hid);
    for (int j = 0; j < 70; ++j) {
        float acc = dot64(w2t + 2560 + j * 64, hid, cov_b2[j]);
        out_mk[(mkbase + j / 7) * 11 + 4 + j % 7] = acc;
    }

    // ---- rebuild LDS column as taf_ = [blend_feat, blend_tf, temb] ----
#pragma unroll
    for (int d = 0; d < DD; ++d) {
        float v = xl[d * TBLK + tid];
        xl[d * TBLK + tid] = kf * v + (1.0f - kf) * kn_f[d];
    }
#pragma unroll
    for (int c = 0; c < CC; ++c) {  // dest 32+c reads src 35+c: safe ascending
        float v = xl[(35 + c) * TBLK + tid];
        xl[(32 + c) * TBLK + tid] = kf * v + (1.0f - kf) * kn_t[c];
    }
    // temb: sin/cos of f32-rounded pi*2^(n-1), compile-time constants
    const float temb_s[8] = {1.0f,          -8.742278e-08f, 1.7484556e-07f,
                             3.4969112e-07f, 6.9938224e-07f, 1.3987645e-06f,
                             2.7975290e-06f, 5.5950579e-06f};
    const float temb_c[8] = {-4.371139e-08f, -1.0f, 1.0f, 1.0f,
                             1.0f,           1.0f,  1.0f, 1.0f};
#pragma unroll
    for (int q = 0; q < 8; ++q) {
        xl[(48 + q) * TBLK + tid] = temb_s[q];
        xl[(56 + q) * TBLK + tid] = temb_c[q];
    }

    // ---- MOTION head: *mf -> out_m[0..36] ----
    hidden_layer<64>(mot_w1, mot_b1, xl, tid, hid);
    float* om = out_m + (size_t)p * 50;
    for (int j = 0; j < 37; ++j) {
        float acc = dot64(w2t + 7040 + j * 64, hid, mot_b2[j]);
        om[j] = acc * mf;
    }

    // ---- out_m tail: exp(scales) (last 3 * pf), factors, anchor ----
    const float2* sp = (const float2*)(scales + (size_t)vid * 6);
    float2 s0 = sp[0], s1 = sp[1], s2 = sp[2];
    om[37] = expf(s0.x);
    om[38] = expf(s0.y);
    om[39] = expf(s1.x);
    om[40] = expf(s1.y) * pf;
    om[41] = expf(s2.x) * pf;
    om[42] = expf(s2.y) * pf;
    om[43] = tff;
    om[44] = mf;
    om[45] = kf;
    om[46] = pf;
    om[47] = ax;
    om[48] = ay;
    om[49] = az;
}

extern "C" void kernel_launch(void* const* d_in, const int* in_sizes, int n_in,
                              void* d_out, int out_size, void* d_ws,
                              size_t ws_size, hipStream_t stream) {
    (void)in_sizes;
    (void)n_in;
    (void)out_size;
    (void)ws_size;
    const float* cam = (const float*)d_in[0];
    const float* anchors = (const float*)d_in[1];
    const float* scales = (const float*)d_in[2];
    const float* feat = (const float*)d_in[3];
    const float* timef = (const float*)d_in[4];
    const float* factors = (const float*)d_in[5];
    const float* op_w1 = (const float*)d_in[6];
    const float* op_b1 = (const float*)d_in[7];
    const float* op_w2 = (const float*)d_in[8];
    const float* op_b2 = (const float*)d_in[9];
    const float* col_w1 = (const float*)d_in[10];
    const float* col_b1 = (const float*)d_in[11];
    const float* col_w2 = (const float*)d_in[12];
    const float* col_b2 = (const float*)d_in[13];
    const float* cov_w1 = (const float*)d_in[14];
    const float* cov_b1 = (const float*)d_in[15];
    const float* cov_w2 = (const float*)d_in[16];
    const float* cov_b2 = (const float*)d_in[17];
    const float* mot_w1 = (const float*)d_in[18];
    const float* mot_b1 = (const float*)d_in[19];
    const float* mot_w2 = (const float*)d_in[20];
    const float* mot_b2 = (const float*)d_in[21];
    const int* visible_idx = (const int*)d_in[22];
    const int* knn_idx = (const int*)d_in[23];

    float* w2t = (float*)d_ws;  // 9408 floats of scratch
    transpose_w2_kernel<<<(640 + 255) / 256, 256, 0, stream>>>(op_w2, w2t, 10);
    transpose_w2_kernel<<<(1920 + 255) / 256, 256, 0, stream>>>(col_w2,
                                                                w2t + 640, 30);
    transpose_w2_kernel<<<(4480 + 255) / 256, 256, 0, stream>>>(cov_w2,
                                                                w2t + 2560, 70);
    transpose_w2_kernel<<<(2368 + 255) / 256, 256, 0, stream>>>(mot_w2,
                                                                w2t + 7040, 37);

    float* out_mk = (float*)d_out;
    float* out_m = out_mk + (size_t)MM * 10 * 11;
    gif_main_kernel<<<(MM + TBLK - 1) / TBLK, TBLK, 0, stream>>>(
        cam, anchors, scales, feat, timef, factors, op_w1, op_b1, op_b2,
        col_w1, col_b1, col_b2, cov_w1, cov_b1, cov_b2, mot_w1, mot_b1, mot_b2,
        w2t, visible_idx, knn_idx, out_mk, out_m);
}